// Round 7
// baseline (300.144 us; speedup 1.0000x reference)
//
#include <hip/hip_runtime.h>

#define E_EDGES 32768
#define NN 8192
#define HID 128
#define KS 4

typedef _Float16 half8 __attribute__((ext_vector_type(8)));
typedef _Float16 half4 __attribute__((ext_vector_type(4)));
typedef float f32x4 __attribute__((ext_vector_type(4)));

// ---------------- CSR build (by dst), done once per call ----------------
__global__ void hist_k(const int* __restrict__ dst, int* __restrict__ hist) {
  int e = blockIdx.x * 256 + threadIdx.x;
  if (e < E_EDGES) atomicAdd(&hist[dst[e]], 1);
}

// 1024-thread block scan of 8192 counts: wave shfl scans, 2 barriers total.
__global__ void scan_k(const int* __restrict__ hist, int* __restrict__ roff, int* __restrict__ cursor) {
  __shared__ int wsum[16];
  int t = threadIdx.x;
  int lane = t & 63, wv = t >> 6;
  int base = t * 8;
  int loc[8]; int s = 0;
#pragma unroll
  for (int j = 0; j < 8; ++j) { loc[j] = s; s += hist[base + j]; }
  int inc = s;
#pragma unroll
  for (int off = 1; off < 64; off <<= 1) {
    int u = __shfl_up(inc, off, 64);
    if (lane >= off) inc += u;
  }
  if (lane == 63) wsum[wv] = inc;
  __syncthreads();
  if (t < 64) {
    int u = (t < 16) ? wsum[t] : 0;
#pragma unroll
    for (int off = 1; off < 16; off <<= 1) {
      int x = __shfl_up(u, off, 64);
      if (lane >= off) u += x;
    }
    if (t < 16) wsum[t] = u;
  }
  __syncthreads();
  int excl = (wv ? wsum[wv - 1] : 0) + inc - s;
#pragma unroll
  for (int j = 0; j < 8; ++j) { int v = excl + loc[j]; roff[base + j] = v; cursor[base + j] = v; }
  if (t == 1023) roff[NN] = wsum[15];
}

__global__ void scatter_k(const int* __restrict__ dst, int* __restrict__ cursor, int* __restrict__ eidx) {
  int e = blockIdx.x * 256 + threadIdx.x;
  if (e < E_EDGES) { int p = atomicAdd(&cursor[dst[e]], 1); eidx[p] = e; }
}

// ---------------- W2 -> f16 B-matrix, round-linear fragment layout -------
// half8 index h8 = (c*FC + fc)*64 + lane; element j: k = c*32 + quad*8 + j,
// n = fc*16 + l15. k<128*CI: theta row W2[k*CO+n]; next CI rows: b2; zero pad.
// Thread-per-h8: wave reads 64B-contiguous W2 slices, writes one half8 (16B).
template <int CI, int CO>
__device__ inline void prep8(int h8, const float* __restrict__ W2,
                             const float* __restrict__ b2, _Float16* __restrict__ out) {
  constexpr int Kmain = 128 * CI;
  constexpr int FC = CO / 16;
  int lane = h8 & 63;
  int quad = lane >> 4, l15 = lane & 15;
  int rest = h8 >> 6;
  int fc = rest & (FC - 1);
  int c = rest / FC;
  int k0 = c * 32 + quad * 8;
  int n = fc * 16 + l15;
  half8 r;
#pragma unroll
  for (int j = 0; j < 8; ++j) {
    int k = k0 + j;
    float v = 0.f;
    if (k < Kmain) v = W2[(size_t)k * CO + n];
    else if (k < Kmain + CI) v = b2[(k - Kmain) * CO + n];
    r[j] = (_Float16)v;
  }
  *(half8*)(out + (size_t)h8 * 8) = r;
}

// fused: B-prep for all 3 layers + zero hist + zero pool accumulators
__global__ void prep_zero_k(const float* __restrict__ W2_0, const float* __restrict__ b2_0, _Float16* __restrict__ o0,
                            const float* __restrict__ W2_1, const float* __restrict__ b2_1, _Float16* __restrict__ o1,
                            const float* __restrict__ W2_2, const float* __restrict__ b2_2, _Float16* __restrict__ o2,
                            int4* __restrict__ hist4, float4* __restrict__ pools4) {
  constexpr int H0 = 2176 * 32 / 8;     // 8704
  constexpr int H1 = 4224 * 64 / 8;     // 33792
  constexpr int H2 = 8320 * 64 / 8;     // 66560
  constexpr int HT = H0 + H1 + H2;      // 109056
  constexpr int ZH = NN / 4;            // 2048
  constexpr int ZP = (512 * 64 + 512) / 4;  // 8320
  int tid = blockIdx.x * 256 + threadIdx.x;
  if (tid < H0) prep8<16, 32>(tid, W2_0, b2_0, o0);
  else if (tid < H0 + H1) prep8<32, 64>(tid - H0, W2_1, b2_1, o1);
  else if (tid < HT) prep8<64, 64>(tid - H0 - H1, W2_2, b2_2, o2);
  else if (tid < HT + ZH) hist4[tid - HT] = int4{0, 0, 0, 0};
  else if (tid < HT + ZH + ZP) pools4[tid - HT - ZH] = float4{0.f, 0.f, 0.f, 0.f};
}

__device__ inline half8 pack8(float4 a, float4 b) {
  half8 r;
  r[0] = (_Float16)a.x; r[1] = (_Float16)a.y; r[2] = (_Float16)a.z; r[3] = (_Float16)a.w;
  r[4] = (_Float16)b.x; r[5] = (_Float16)b.y; r[6] = (_Float16)b.z; r[7] = (_Float16)b.w;
  return r;
}

// async global->LDS, 16 B per lane, linear dest (wave-uniform base + lane*16)
__device__ __forceinline__ void gload_lds16(const _Float16* g, _Float16* l) {
  __builtin_amdgcn_global_load_lds(
      (__attribute__((address_space(1))) void*)(size_t)(const void*)g,
      (__attribute__((address_space(3))) void*)(size_t)(void*)l, 16, 0, 0);
}

// ---------------- main fused kernel: edge MLP1 + Z@W2r GEMM (split-K=4) ---
// SORTED-EDGE: block handles sorted positions p in [e0, e0+128); messages
// land at msgbuf[p*KS+y] so gather reads are contiguous per node.
// AMPLIFICATION-1 wave decomposition (the one change this round): ME=128,
// 4 waves. CO=64: pure column split (wn=w owns 16 cols, FR=8 row-frags for
// ALL 128 edges) -> each B fragment is ds_read exactly ONCE per block
// (r6: 4x -- every wave read all fragments; LDS 768 cyc/round vs 192 now).
// CO=32: 2x2 split (amp 2). B round-tiles staged per block via
// global_load_lds (double-buffered), counted vmcnt, 2 s_barriers/round.
template <int CI, int CO>
__launch_bounds__(256, 2)
__global__ void msg_mfma_k(const float* __restrict__ xcur, const int* __restrict__ src,
                           const int* __restrict__ eidx,
                           const float* __restrict__ eattr, const float* __restrict__ W1,
                           const float* __restrict__ b1, const _Float16* __restrict__ Bsw,
                           float* __restrict__ msgbuf) {
  constexpr int ME = 128;                      // edges per block
  constexpr int HSTR = 36;                     // he [e][36] f16: 72B rows -> conflict-free
  constexpr int FC = CO / 16;
  constexpr int WN = (FC == 4) ? 4 : 2;        // column-split waves
  constexpr int WE = 4 / WN;                   // edge-split waves
  constexpr int FR = (ME / 16) / WE;           // row fragments per wave (8 or 4)
  constexpr int NMAIN = CI / 4;                // main rounds per split
  constexpr int XPN = (CI == 64) ? 2 : 1;
  constexpr int RHALF = 4 * FC * 64 * 8;       // halfs per round tile (8192/4096)

  __shared__ _Float16 he_s[ME * HSTR];
  __shared__ float ea_s[ME * 5];
  __shared__ float W1s[5 * 32];
  __shared__ float b1s[32];
  __shared__ int src_s[ME];
  __shared__ _Float16 bls[2 * RHALF];          // B round double-buffer

  int t = threadIdx.x;
  int e0 = blockIdx.x * ME;
  int y = blockIdx.y;                          // split: h in [32y, 32y+32)
  int hbeg = y * 32;

  // phase 1: gather per-edge eattr rows + src via sorted permutation
  if (t < ME) {
    int eg = eidx[e0 + t];
    src_s[t] = src[eg];
#pragma unroll
    for (int d = 0; d < 5; ++d) ea_s[t * 5 + d] = eattr[eg * 5 + d];
  }
  if (t < 5 * 32) W1s[t] = W1[(t >> 5) * HID + hbeg + (t & 31)];
  if (t < 32) b1s[t] = b1[hbeg + t];
  __syncthreads();

  // phase 2: edge MLP1 (this split's 32 h). hl fastest: 2B-contiguous stores.
  for (int j = t; j < 32 * ME; j += 256) {
    int hl = j & 31, e = j >> 5;
    float v = b1s[hl];
#pragma unroll
    for (int d = 0; d < 5; ++d) v += ea_s[e * 5 + d] * W1s[d * 32 + hl];
    he_s[e * HSTR + hl] = (_Float16)fmaxf(v, 0.f);
  }
  __syncthreads();

  int lane = t & 63;
  int w = t >> 6;
  int wn = w % WN, we = w / WN;                // column / edge wave role
  int quad = lane >> 4, l15 = lane & 15;
  int qsh = (quad >> 1) << 4;                  // CI==16 h-pair select shift
  int Rg0 = y * NMAIN;                         // first global round of split
  int NR = NMAIN + ((y == 3) ? 1 : 0);         // +1 tail round on y==3

  // one-time preload: x fragments direct from global, he row offsets
  half8 xp[FR][XPN];
  int hoff[FR];
#pragma unroll
  for (int fr = 0; fr < FR; ++fr) {
    int e = we * (FR * 16) + fr * 16 + l15;
    const float* xr = xcur + (size_t)src_s[e] * CI;
    int i0 = (CI == 16) ? ((quad & 1) * 8) : (quad * 8);
    float4 v0 = *(const float4*)(xr + i0);
    float4 v1 = *(const float4*)(xr + i0 + 4);
    xp[fr][0] = pack8(v0, v1);
    if constexpr (CI == 64) {
      float4 v2 = *(const float4*)(xr + i0 + 32);
      float4 v3 = *(const float4*)(xr + i0 + 36);
      xp[fr][1] = pack8(v2, v3);
    }
    hoff[fr] = e * HSTR;
  }

  f32x4 acc[FR];
#pragma unroll
  for (int fr = 0; fr < FR; ++fr)
#pragma unroll
    for (int r = 0; r < 4; ++r) acc[fr][r] = 0.f;

  // stage one round-tile: FC x 1KB per wave (w-indexed quarter), lane x 16B
  auto stageR = [&](int rg, int buf) {
    const _Float16* gb = Bsw + (size_t)rg * RHALF + w * (FC * 512);
    _Float16* lb = bls + buf * RHALF + w * (FC * 512);
#pragma unroll
    for (int i = 0; i < FC; ++i)
      gload_lds16(gb + i * 512 + lane * 8, lb + i * 512);
  };

  // prologue: stage rounds 0 and 1
  stageR(Rg0, 0);
  stageR(Rg0 + 1, 1);

  for (int r = 0; r < NR; ++r) {
    // wait for this round's stage; keep next round's FC loads in flight
    if (r + 1 < NR) {
      if constexpr (FC == 4) asm volatile("s_waitcnt vmcnt(4)" ::: "memory");
      else                   asm volatile("s_waitcnt vmcnt(2)" ::: "memory");
    } else {
      asm volatile("s_waitcnt vmcnt(0)" ::: "memory");
    }
    __builtin_amdgcn_s_barrier();

    const _Float16* bp = bls + (r & 1) * RHALF;
    int c0 = (Rg0 + r) * 4;

    if (r < NMAIN) {
      unsigned int hp2[FR];                    // CI==64: {h0, h0+1}
      half4 hp4[FR];                           // CI==32: {h0..h0+3}
      if constexpr (CI == 64) {
        int oh = (c0 >> 1) - hbeg;
#pragma unroll
        for (int fr = 0; fr < FR; ++fr) hp2[fr] = *(const unsigned int*)(he_s + hoff[fr] + oh);
      } else if constexpr (CI == 32) {
        int oh = c0 - hbeg;
#pragma unroll
        for (int fr = 0; fr < FR; ++fr) hp4[fr] = *(const half4*)(he_s + hoff[fr] + oh);
      }
#pragma unroll
      for (int cr = 0; cr < 4; ++cr) {
        int c = c0 + cr;
        // this wave's single B fragment for chunk cr
        half8 bf = *(const half8*)&bp[((cr * FC + wn) * 64 + lane) * 8];
#pragma unroll
        for (int fr = 0; fr < FR; ++fr) {
          half8 a;
          if constexpr (CI == 64) {
            unsigned short hb = (unsigned short)((cr >= 2) ? (hp2[fr] >> 16) : hp2[fr]);
            _Float16 hv = __builtin_bit_cast(_Float16, hb);
            a = xp[fr][cr & 1] * hv;
          } else if constexpr (CI == 32) {
            a = xp[fr][0] * hp4[fr][cr];
          } else {
            unsigned int hw = *(const unsigned int*)(he_s + hoff[fr] + (2 * c - hbeg));
            _Float16 hv = __builtin_bit_cast(_Float16, (unsigned short)(hw >> qsh));
            a = xp[fr][0] * hv;
          }
          acc[fr] = __builtin_amdgcn_mfma_f32_16x16x32_f16(a, bf, acc[fr], 0, 0, 0);
        }
      }
    } else {
      // tail round (y==3): b2 rows, he == 1; B zero-padded beyond CI rows
#pragma unroll
      for (int cr = 0; cr < 4; ++cr) {
        half8 bf = *(const half8*)&bp[((cr * FC + wn) * 64 + lane) * 8];
#pragma unroll
        for (int fr = 0; fr < FR; ++fr) {
          half8 a = xp[fr][(CI == 64) ? (cr & 1) : 0];
          acc[fr] = __builtin_amdgcn_mfma_f32_16x16x32_f16(a, bf, acc[fr], 0, 0, 0);
        }
      }
    }

    // all ds_reads of this buffer complete before anyone re-stages it
    asm volatile("s_waitcnt lgkmcnt(0)" ::: "memory");
    __builtin_amdgcn_s_barrier();
    if (r + 2 < NR) stageR(Rg0 + r + 2, r & 1);
  }

  // epilogue: write message of sorted position p to msgbuf[(p*KS + y)*CO]
  // C/D: row(e) = quad*4 + r, col(o) = l15 within this wave's 16-col slice
#pragma unroll
  for (int fr = 0; fr < FR; ++fr)
#pragma unroll
    for (int r = 0; r < 4; ++r) {
      int el = we * (FR * 16) + fr * 16 + quad * 4 + r;
      int o = wn * 16 + l15;
      msgbuf[((size_t)(e0 + el) * KS + y) * CO + o] = acc[fr][r];
    }
}

// ---------------- scatter-sum: CONTIGUOUS msgbuf streams + x@root + ELU ---
// Messages are dst-sorted: node n owns rows [roff[n], roff[n+1]) x KS x CO,
// a fully contiguous region -- pure streaming reads, no indirection.
// POOL=true (last layer): skip x-write, atomically accumulate subgraph pools.
template <int CI, int CO, bool POOL>
__global__ void gather_elu_k(const float* __restrict__ xcur, const float* __restrict__ root,
                             const float* __restrict__ bias, const float* __restrict__ msgbuf,
                             const int* __restrict__ roff,
                             float* __restrict__ xnext, const int* __restrict__ n2s,
                             float* __restrict__ ssum, float* __restrict__ scnt) {
  constexpr int OV = CO / 4;                   // float4 lanes per node (8/16)
  constexpr int NB = 256 / OV;                 // nodes per block (32/16)
  __shared__ float xs[NB * CI];
  int t = threadIdx.x;
  int n0 = blockIdx.x * NB;
  for (int j = t; j < NB * CI; j += 256) xs[j] = xcur[n0 * CI + j];
  __syncthreads();
  int nl = t / OV, o4 = t & (OV - 1);
  int n = n0 + nl;
  float4 a = ((const float4*)bias)[o4];
  const float4* root4 = (const float4*)root;
#pragma unroll
  for (int i = 0; i < CI; ++i) {
    float xv = xs[nl * CI + i];
    float4 rv = root4[i * OV + o4];
    a.x += xv * rv.x; a.y += xv * rv.y; a.z += xv * rv.z; a.w += xv * rv.w;
  }
  int j1 = roff[n + 1];
  const float4* mb4 = (const float4*)msgbuf;
  for (int p = roff[n]; p < j1; ++p) {
#pragma unroll
    for (int s = 0; s < KS; ++s) {
      float4 m = mb4[((size_t)p * KS + s) * OV + o4];
      a.x += m.x; a.y += m.y; a.z += m.z; a.w += m.w;
    }
  }
  float4 v;
  v.x = a.x > 0.f ? a.x : expm1f(a.x);
  v.y = a.y > 0.f ? a.y : expm1f(a.y);
  v.z = a.z > 0.f ? a.z : expm1f(a.z);
  v.w = a.w > 0.f ? a.w : expm1f(a.w);
  if constexpr (POOL) {
    int s = n2s[n];
    float* sb = &ssum[(s << 6) + o4 * 4];
    atomicAdd(sb + 0, v.x); atomicAdd(sb + 1, v.y);
    atomicAdd(sb + 2, v.z); atomicAdd(sb + 3, v.w);
    if (o4 == 0) atomicAdd(&scnt[s], 1.f);
  } else {
    ((float4*)xnext)[(size_t)n * OV + o4] = v;
  }
}

// ---------------- graph pooling + MLP head (fused) ------------------------
__global__ void pg_head_k(const float* __restrict__ ssum, const float* __restrict__ scnt,
                          const int* __restrict__ s2g,
                          const float* __restrict__ w1, const float* __restrict__ b1,
                          const float* __restrict__ w2, const float* __restrict__ b2,
                          const float* __restrict__ w3, const float* __restrict__ b3,
                          float* __restrict__ out) {
  int g = blockIdx.x;
  int t = threadIdx.x;  // 64 threads
  __shared__ int s2s[512];
  __shared__ float hm[64], h1[32], h2[16];
  for (int i = t; i < 512; i += 64) s2s[i] = s2g[i];
  __syncthreads();
  float acc = 0.f, cnt = 0.f;
  for (int s = 0; s < 512; ++s) {
    if (s2s[s] == g) {
      acc += ssum[(s << 6) + t] / fmaxf(scnt[s], 1.f);
      cnt += 1.f;
    }
  }
  hm[t] = acc / fmaxf(cnt, 1.f);
  __syncthreads();
  if (t < 32) {
    float a = b1[t];
    for (int i = 0; i < 64; ++i) a += hm[i] * w1[i * 32 + t];
    h1[t] = a > 0.f ? a : expm1f(a);
  }
  __syncthreads();
  if (t < 16) {
    float a = b2[t];
    for (int i = 0; i < 32; ++i) a += h1[i] * w2[i * 16 + t];
    h2[t] = a > 0.f ? a : expm1f(a);
  }
  __syncthreads();
  if (t == 0) {
    float a = b3[0];
    for (int i = 0; i < 16; ++i) a += h2[i] * w3[i];
    out[g] = a;
  }
}

extern "C" void kernel_launch(void* const* d_in, const int* in_sizes, int n_in,
                              void* d_out, int out_size, void* d_ws, size_t ws_size,
                              hipStream_t stream) {
  (void)in_sizes; (void)n_in; (void)out_size; (void)ws_size;
  const float* x0 = (const float*)d_in[0];
  const int* ei = (const int*)d_in[1];
  const float* ea = (const float*)d_in[2];
  const int* n2s = (const int*)d_in[3];
  const int* s2g = (const int*)d_in[4];
  const float* W1_[3] = {(const float*)d_in[5], (const float*)d_in[11], (const float*)d_in[17]};
  const float* b1_[3] = {(const float*)d_in[6], (const float*)d_in[12], (const float*)d_in[18]};
  const float* W2_[3] = {(const float*)d_in[7], (const float*)d_in[13], (const float*)d_in[19]};
  const float* b2_[3] = {(const float*)d_in[8], (const float*)d_in[14], (const float*)d_in[20]};
  const float* rt_[3] = {(const float*)d_in[9], (const float*)d_in[15], (const float*)d_in[21]};
  const float* bs_[3] = {(const float*)d_in[10], (const float*)d_in[16], (const float*)d_in[22]};
  const float* fc1w = (const float*)d_in[23]; const float* fc1b = (const float*)d_in[24];
  const float* fc2w = (const float*)d_in[25]; const float* fc2b = (const float*)d_in[26];
  const float* fc3w = (const float*)d_in[27]; const float* fc3b = (const float*)d_in[28];
  float* out = (float*)d_out;

  const int* srcp = ei;
  const int* dstp = ei + E_EDGES;

  char* wsb = (char*)d_ws;
  size_t off = 0;
  auto alloc = [&](size_t bytes) {
    void* p = wsb + off;
    off += (bytes + 255) & ~(size_t)255;
    return p;
  };
  // Kpad: L0(CI=16): 2176, L1(CI=32): 4224, L2(CI=64): 8320
  _Float16* Bsw0 = (_Float16*)alloc((size_t)2176 * 32 * 2);
  _Float16* Bsw1 = (_Float16*)alloc((size_t)4224 * 64 * 2);
  _Float16* Bsw2 = (_Float16*)alloc((size_t)8320 * 64 * 2);
  float* msgbuf = (float*)alloc((size_t)KS * E_EDGES * 64 * 4);
  float* x1 = (float*)alloc((size_t)NN * 32 * 4);
  float* x2 = (float*)alloc((size_t)NN * 64 * 4);
  int* hist = (int*)alloc((size_t)NN * 4);
  int* roff = (int*)alloc((size_t)(NN + 1) * 4);
  int* cursor = (int*)alloc((size_t)NN * 4);
  int* eidx = (int*)alloc((size_t)E_EDGES * 4);
  const int npool = 512 * 64 + 512;
  float* pools = (float*)alloc((size_t)npool * 4);
  float* ssum = pools;
  float* scnt = pools + 512 * 64;

  // fused prep+zero: 109056 h8 threads + 2048 hist-int4 + 8320 pool-float4
  const int nprep = 109056 + 2048 + 8320;
  prep_zero_k<<<(nprep + 255) / 256, 256, 0, stream>>>(
      W2_[0], b2_[0], Bsw0, W2_[1], b2_[1], Bsw1, W2_[2], b2_[2], Bsw2,
      (int4*)hist, (float4*)pools);
  hist_k<<<E_EDGES / 256, 256, 0, stream>>>(dstp, hist);
  scan_k<<<1, 1024, 0, stream>>>(hist, roff, cursor);
  scatter_k<<<E_EDGES / 256, 256, 0, stream>>>(dstp, cursor, eidx);

  dim3 mg(E_EDGES / 128, KS);
  msg_mfma_k<16, 32><<<mg, 256, 0, stream>>>(x0, srcp, eidx, ea, W1_[0], b1_[0], Bsw0, msgbuf);
  gather_elu_k<16, 32, false><<<NN / 32, 256, 0, stream>>>(x0, rt_[0], bs_[0], msgbuf, roff, x1, nullptr, nullptr, nullptr);
  msg_mfma_k<32, 64><<<mg, 256, 0, stream>>>(x1, srcp, eidx, ea, W1_[1], b1_[1], Bsw1, msgbuf);
  gather_elu_k<32, 64, false><<<NN / 16, 256, 0, stream>>>(x1, rt_[1], bs_[1], msgbuf, roff, x2, nullptr, nullptr, nullptr);
  msg_mfma_k<64, 64><<<mg, 256, 0, stream>>>(x2, srcp, eidx, ea, W1_[2], b1_[2], Bsw2, msgbuf);
  gather_elu_k<64, 64, true><<<NN / 16, 256, 0, stream>>>(x2, rt_[2], bs_[2], msgbuf, roff, nullptr, n2s, ssum, scnt);

  pg_head_k<<<32, 64, 0, stream>>>(ssum, scnt, s2g, fc1w, fc1b, fc2w, fc2b, fc3w, fc3b, out);
}

// Round 8
// 277.824 us; speedup vs baseline: 1.0803x; 1.0803x over previous
//
#include <hip/hip_runtime.h>

#define E_EDGES 32768
#define NN 8192
#define HID 128
#define KS 4

typedef _Float16 half8 __attribute__((ext_vector_type(8)));
typedef _Float16 half4 __attribute__((ext_vector_type(4)));
typedef float f32x4 __attribute__((ext_vector_type(4)));

// ---------------- CSR build (by dst), done once per call ----------------
__global__ void hist_k(const int* __restrict__ dst, int* __restrict__ hist) {
  int e = blockIdx.x * 256 + threadIdx.x;
  if (e < E_EDGES) atomicAdd(&hist[dst[e]], 1);
}

// 1024-thread block scan of 8192 counts: wave shfl scans, 2 barriers total.
__global__ void scan_k(const int* __restrict__ hist, int* __restrict__ roff, int* __restrict__ cursor) {
  __shared__ int wsum[16];
  int t = threadIdx.x;
  int lane = t & 63, wv = t >> 6;
  int base = t * 8;
  int loc[8]; int s = 0;
#pragma unroll
  for (int j = 0; j < 8; ++j) { loc[j] = s; s += hist[base + j]; }
  int inc = s;
#pragma unroll
  for (int off = 1; off < 64; off <<= 1) {
    int u = __shfl_up(inc, off, 64);
    if (lane >= off) inc += u;
  }
  if (lane == 63) wsum[wv] = inc;
  __syncthreads();
  if (t < 64) {
    int u = (t < 16) ? wsum[t] : 0;
#pragma unroll
    for (int off = 1; off < 16; off <<= 1) {
      int x = __shfl_up(u, off, 64);
      if (lane >= off) u += x;
    }
    if (t < 16) wsum[t] = u;
  }
  __syncthreads();
  int excl = (wv ? wsum[wv - 1] : 0) + inc - s;
#pragma unroll
  for (int j = 0; j < 8; ++j) { int v = excl + loc[j]; roff[base + j] = v; cursor[base + j] = v; }
  if (t == 1023) roff[NN] = wsum[15];
}

__global__ void scatter_k(const int* __restrict__ dst, int* __restrict__ cursor, int* __restrict__ eidx) {
  int e = blockIdx.x * 256 + threadIdx.x;
  if (e < E_EDGES) { int p = atomicAdd(&cursor[dst[e]], 1); eidx[p] = e; }
}

// ---------------- W2 -> f16 B-matrix, round-linear fragment layout -------
// half8 index h8 = (c*FC + fc)*64 + lane; element j: k = c*32 + quad*8 + j,
// n = fc*16 + l15. k<128*CI: theta row W2[k*CO+n]; next CI rows: b2; zero pad.
// Thread-per-h8: wave reads 64B-contiguous W2 slices, writes one half8 (16B).
template <int CI, int CO>
__device__ inline void prep8(int h8, const float* __restrict__ W2,
                             const float* __restrict__ b2, _Float16* __restrict__ out) {
  constexpr int Kmain = 128 * CI;
  constexpr int FC = CO / 16;
  int lane = h8 & 63;
  int quad = lane >> 4, l15 = lane & 15;
  int rest = h8 >> 6;
  int fc = rest & (FC - 1);
  int c = rest / FC;
  int k0 = c * 32 + quad * 8;
  int n = fc * 16 + l15;
  half8 r;
#pragma unroll
  for (int j = 0; j < 8; ++j) {
    int k = k0 + j;
    float v = 0.f;
    if (k < Kmain) v = W2[(size_t)k * CO + n];
    else if (k < Kmain + CI) v = b2[(k - Kmain) * CO + n];
    r[j] = (_Float16)v;
  }
  *(half8*)(out + (size_t)h8 * 8) = r;
}

// fused: B-prep for all 3 layers + zero hist + zero pool accumulators
__global__ void prep_zero_k(const float* __restrict__ W2_0, const float* __restrict__ b2_0, _Float16* __restrict__ o0,
                            const float* __restrict__ W2_1, const float* __restrict__ b2_1, _Float16* __restrict__ o1,
                            const float* __restrict__ W2_2, const float* __restrict__ b2_2, _Float16* __restrict__ o2,
                            int4* __restrict__ hist4, float4* __restrict__ pools4) {
  constexpr int H0 = 2176 * 32 / 8;     // 8704
  constexpr int H1 = 4224 * 64 / 8;     // 33792
  constexpr int H2 = 8320 * 64 / 8;     // 66560
  constexpr int HT = H0 + H1 + H2;      // 109056
  constexpr int ZH = NN / 4;            // 2048
  constexpr int ZP = (512 * 64 + 512) / 4;  // 8320
  int tid = blockIdx.x * 256 + threadIdx.x;
  if (tid < H0) prep8<16, 32>(tid, W2_0, b2_0, o0);
  else if (tid < H0 + H1) prep8<32, 64>(tid - H0, W2_1, b2_1, o1);
  else if (tid < HT) prep8<64, 64>(tid - H0 - H1, W2_2, b2_2, o2);
  else if (tid < HT + ZH) hist4[tid - HT] = int4{0, 0, 0, 0};
  else if (tid < HT + ZH + ZP) pools4[tid - HT - ZH] = float4{0.f, 0.f, 0.f, 0.f};
}

__device__ inline half8 pack8(float4 a, float4 b) {
  half8 r;
  r[0] = (_Float16)a.x; r[1] = (_Float16)a.y; r[2] = (_Float16)a.z; r[3] = (_Float16)a.w;
  r[4] = (_Float16)b.x; r[5] = (_Float16)b.y; r[6] = (_Float16)b.z; r[7] = (_Float16)b.w;
  return r;
}

// async global->LDS, 16 B per lane, linear dest (wave-uniform base + lane*16)
__device__ __forceinline__ void gload_lds16(const _Float16* g, _Float16* l) {
  __builtin_amdgcn_global_load_lds(
      (__attribute__((address_space(1))) void*)(size_t)(const void*)g,
      (__attribute__((address_space(3))) void*)(size_t)(void*)l, 16, 0, 0);
}

// ---------------- main fused kernel: edge MLP1 + Z@W2r GEMM (split-K=4) ---
// SORTED-EDGE variant: block handles sorted positions p in [e0, e0+256);
// edge identity e = eidx[p] (dst-sorted). Messages land at msgbuf[p*KS+y],
// so the downstream gather reads are fully CONTIGUOUS per node.
// Measured-best geometry (R4/R6): ME=256, 4 waves, fr=4, amp-4 (each wave
// reads all FC B-fragments but owns its 64 edges' A-side exclusively --
// R7 showed amp-1 column split duplicates A-compute and regresses).
// B round-tiles staged once per block via global_load_lds (double-buffered,
// shared by 4 waves), counted vmcnt (never 0 mid-loop), 2 s_barriers/round.
template <int CI, int CO>
__launch_bounds__(256, 2)
__global__ void msg_mfma_k(const float* __restrict__ xcur, const int* __restrict__ src,
                           const int* __restrict__ eidx,
                           const float* __restrict__ eattr, const float* __restrict__ W1,
                           const float* __restrict__ b1, const _Float16* __restrict__ Bsw,
                           float* __restrict__ msgbuf) {
  constexpr int ME = 256;                      // edges per block
  constexpr int HSTR = 36;                     // he [e][36] f16: 72B rows -> conflict-free
  constexpr int FC = CO / 16;
  constexpr int NMAIN = CI / 4;                // main rounds per split
  constexpr int XPN = (CI == 64) ? 2 : 1;
  constexpr int RHALF = 4 * FC * 64 * 8;       // halfs per round tile (8192/4096)

  __shared__ _Float16 he_s[ME * HSTR];
  __shared__ float ea_s[ME * 5];
  __shared__ float W1s[5 * 32];
  __shared__ float b1s[32];
  __shared__ int src_s[ME];
  __shared__ _Float16 bls[2 * RHALF];          // B round double-buffer

  int t = threadIdx.x;
  int e0 = blockIdx.x * ME;
  int y = blockIdx.y;                          // split: h in [32y, 32y+32)
  int hbeg = y * 32;

  // phase 1: gather per-edge eattr rows + src via sorted permutation
  {
    int eg = eidx[e0 + t];
    src_s[t] = src[eg];
#pragma unroll
    for (int d = 0; d < 5; ++d) ea_s[t * 5 + d] = eattr[eg * 5 + d];
  }
  if (t < 5 * 32) W1s[t] = W1[(t >> 5) * HID + hbeg + (t & 31)];
  if (t < 32) b1s[t] = b1[hbeg + t];
  __syncthreads();

  // phase 2: edge MLP1 (this split's 32 h). hl fastest: 2B-contiguous stores.
  for (int j = t; j < 32 * ME; j += 256) {
    int hl = j & 31, e = j >> 5;
    float v = b1s[hl];
#pragma unroll
    for (int d = 0; d < 5; ++d) v += ea_s[e * 5 + d] * W1s[d * 32 + hl];
    he_s[e * HSTR + hl] = (_Float16)fmaxf(v, 0.f);
  }
  __syncthreads();

  int lane = t & 63;
  int w = t >> 6;
  int quad = lane >> 4, l15 = lane & 15;
  int qsh = (quad >> 1) << 4;                  // CI==16 h-pair select shift
  int Rg0 = y * NMAIN;                         // first global round of split
  int NR = NMAIN + ((y == 3) ? 1 : 0);         // +1 tail round on y==3

  // one-time preload: x fragments direct from global, he row offsets
  half8 xp[4][XPN];
  int hoff[4];
#pragma unroll
  for (int fr = 0; fr < 4; ++fr) {
    int e = w * 64 + fr * 16 + l15;
    const float* xr = xcur + (size_t)src_s[e] * CI;
    int i0 = (CI == 16) ? ((quad & 1) * 8) : (quad * 8);
    float4 v0 = *(const float4*)(xr + i0);
    float4 v1 = *(const float4*)(xr + i0 + 4);
    xp[fr][0] = pack8(v0, v1);
    if constexpr (CI == 64) {
      float4 v2 = *(const float4*)(xr + i0 + 32);
      float4 v3 = *(const float4*)(xr + i0 + 36);
      xp[fr][1] = pack8(v2, v3);
    }
    hoff[fr] = e * HSTR;
  }

  f32x4 acc[4][FC];
#pragma unroll
  for (int fr = 0; fr < 4; ++fr)
#pragma unroll
    for (int fc = 0; fc < FC; ++fc)
#pragma unroll
      for (int r = 0; r < 4; ++r) acc[fr][fc][r] = 0.f;

  // stage one round-tile: FC x 1KB per wave (w-indexed quarter), lane x 16B
  auto stageR = [&](int rg, int buf) {
    const _Float16* gb = Bsw + (size_t)rg * RHALF + w * (FC * 512);
    _Float16* lb = bls + buf * RHALF + w * (FC * 512);
#pragma unroll
    for (int i = 0; i < FC; ++i)
      gload_lds16(gb + i * 512 + lane * 8, lb + i * 512);
  };

  // prologue: stage rounds 0 and 1
  stageR(Rg0, 0);
  stageR(Rg0 + 1, 1);

  for (int r = 0; r < NR; ++r) {
    // wait for this round's stage; keep next round's FC loads in flight
    if (r + 1 < NR) {
      if constexpr (FC == 4) asm volatile("s_waitcnt vmcnt(4)" ::: "memory");
      else                   asm volatile("s_waitcnt vmcnt(2)" ::: "memory");
    } else {
      asm volatile("s_waitcnt vmcnt(0)" ::: "memory");
    }
    __builtin_amdgcn_s_barrier();

    const _Float16* bp = bls + (r & 1) * RHALF;
    int c0 = (Rg0 + r) * 4;

    if (r < NMAIN) {
      unsigned int hp2[4];                     // CI==64: {h0, h0+1}
      half4 hp4[4];                            // CI==32: {h0..h0+3}
      if constexpr (CI == 64) {
        int oh = (c0 >> 1) - hbeg;
#pragma unroll
        for (int fr = 0; fr < 4; ++fr) hp2[fr] = *(const unsigned int*)(he_s + hoff[fr] + oh);
      } else if constexpr (CI == 32) {
        int oh = c0 - hbeg;
#pragma unroll
        for (int fr = 0; fr < 4; ++fr) hp4[fr] = *(const half4*)(he_s + hoff[fr] + oh);
      }
#pragma unroll
      for (int cr = 0; cr < 4; ++cr) {
        int c = c0 + cr;
        half8 a[4];
#pragma unroll
        for (int fr = 0; fr < 4; ++fr) {
          if constexpr (CI == 64) {
            unsigned short hb = (unsigned short)((cr >= 2) ? (hp2[fr] >> 16) : hp2[fr]);
            _Float16 hv = __builtin_bit_cast(_Float16, hb);
            a[fr] = xp[fr][cr & 1] * hv;
          } else if constexpr (CI == 32) {
            a[fr] = xp[fr][0] * hp4[fr][cr];
          } else {
            unsigned int hw = *(const unsigned int*)(he_s + hoff[fr] + (2 * c - hbeg));
            _Float16 hv = __builtin_bit_cast(_Float16, (unsigned short)(hw >> qsh));
            a[fr] = xp[fr][0] * hv;
          }
        }
#pragma unroll
        for (int fc = 0; fc < FC; ++fc) {
          half8 bf = *(const half8*)&bp[((cr * FC + fc) * 64 + lane) * 8];
#pragma unroll
          for (int fr = 0; fr < 4; ++fr)
            acc[fr][fc] = __builtin_amdgcn_mfma_f32_16x16x32_f16(a[fr], bf, acc[fr][fc], 0, 0, 0);
        }
      }
    } else {
      // tail round (y==3): b2 rows, he == 1; B zero-padded beyond CI rows
#pragma unroll
      for (int cr = 0; cr < 4; ++cr) {
        half8 a[4];
#pragma unroll
        for (int fr = 0; fr < 4; ++fr) a[fr] = xp[fr][(CI == 64) ? (cr & 1) : 0];
#pragma unroll
        for (int fc = 0; fc < FC; ++fc) {
          half8 bf = *(const half8*)&bp[((cr * FC + fc) * 64 + lane) * 8];
#pragma unroll
          for (int fr = 0; fr < 4; ++fr)
            acc[fr][fc] = __builtin_amdgcn_mfma_f32_16x16x32_f16(a[fr], bf, acc[fr][fc], 0, 0, 0);
        }
      }
    }

    // all ds_reads of this buffer complete before anyone re-stages it
    asm volatile("s_waitcnt lgkmcnt(0)" ::: "memory");
    __builtin_amdgcn_s_barrier();
    if (r + 2 < NR) stageR(Rg0 + r + 2, r & 1);
  }

  // epilogue: write message of sorted position p to msgbuf[(p*KS + y)*CO]
#pragma unroll
  for (int fr = 0; fr < 4; ++fr)
#pragma unroll
    for (int fc = 0; fc < FC; ++fc)
#pragma unroll
      for (int r = 0; r < 4; ++r) {
        int el = w * 64 + fr * 16 + quad * 4 + r;
        int o = fc * 16 + l15;
        msgbuf[((size_t)(e0 + el) * KS + y) * CO + o] = acc[fr][fc][r];
      }
}

// ---------------- scatter-sum: CONTIGUOUS msgbuf streams + x@root + ELU ---
// Messages are dst-sorted: node n owns rows [roff[n], roff[n+1]) x KS x CO,
// a fully contiguous region -- pure streaming reads, no indirection.
// POOL=true (last layer): skip x-write, atomically accumulate subgraph pools.
template <int CI, int CO, bool POOL>
__global__ void gather_elu_k(const float* __restrict__ xcur, const float* __restrict__ root,
                             const float* __restrict__ bias, const float* __restrict__ msgbuf,
                             const int* __restrict__ roff,
                             float* __restrict__ xnext, const int* __restrict__ n2s,
                             float* __restrict__ ssum, float* __restrict__ scnt) {
  constexpr int OV = CO / 4;                   // float4 lanes per node (8/16)
  constexpr int NB = 256 / OV;                 // nodes per block (32/16)
  __shared__ float xs[NB * CI];
  int t = threadIdx.x;
  int n0 = blockIdx.x * NB;
  for (int j = t; j < NB * CI; j += 256) xs[j] = xcur[n0 * CI + j];
  __syncthreads();
  int nl = t / OV, o4 = t & (OV - 1);
  int n = n0 + nl;
  float4 a = ((const float4*)bias)[o4];
  const float4* root4 = (const float4*)root;
#pragma unroll
  for (int i = 0; i < CI; ++i) {
    float xv = xs[nl * CI + i];
    float4 rv = root4[i * OV + o4];
    a.x += xv * rv.x; a.y += xv * rv.y; a.z += xv * rv.z; a.w += xv * rv.w;
  }
  int j1 = roff[n + 1];
  const float4* mb4 = (const float4*)msgbuf;
  for (int p = roff[n]; p < j1; ++p) {
#pragma unroll
    for (int s = 0; s < KS; ++s) {
      float4 m = mb4[((size_t)p * KS + s) * OV + o4];
      a.x += m.x; a.y += m.y; a.z += m.z; a.w += m.w;
    }
  }
  float4 v;
  v.x = a.x > 0.f ? a.x : expm1f(a.x);
  v.y = a.y > 0.f ? a.y : expm1f(a.y);
  v.z = a.z > 0.f ? a.z : expm1f(a.z);
  v.w = a.w > 0.f ? a.w : expm1f(a.w);
  if constexpr (POOL) {
    int s = n2s[n];
    float* sb = &ssum[(s << 6) + o4 * 4];
    atomicAdd(sb + 0, v.x); atomicAdd(sb + 1, v.y);
    atomicAdd(sb + 2, v.z); atomicAdd(sb + 3, v.w);
    if (o4 == 0) atomicAdd(&scnt[s], 1.f);
  } else {
    ((float4*)xnext)[(size_t)n * OV + o4] = v;
  }
}

// ---------------- graph pooling + MLP head (fused) ------------------------
__global__ void pg_head_k(const float* __restrict__ ssum, const float* __restrict__ scnt,
                          const int* __restrict__ s2g,
                          const float* __restrict__ w1, const float* __restrict__ b1,
                          const float* __restrict__ w2, const float* __restrict__ b2,
                          const float* __restrict__ w3, const float* __restrict__ b3,
                          float* __restrict__ out) {
  int g = blockIdx.x;
  int t = threadIdx.x;  // 64 threads
  __shared__ int s2s[512];
  __shared__ float hm[64], h1[32], h2[16];
  for (int i = t; i < 512; i += 64) s2s[i] = s2g[i];
  __syncthreads();
  float acc = 0.f, cnt = 0.f;
  for (int s = 0; s < 512; ++s) {
    if (s2s[s] == g) {
      acc += ssum[(s << 6) + t] / fmaxf(scnt[s], 1.f);
      cnt += 1.f;
    }
  }
  hm[t] = acc / fmaxf(cnt, 1.f);
  __syncthreads();
  if (t < 32) {
    float a = b1[t];
    for (int i = 0; i < 64; ++i) a += hm[i] * w1[i * 32 + t];
    h1[t] = a > 0.f ? a : expm1f(a);
  }
  __syncthreads();
  if (t < 16) {
    float a = b2[t];
    for (int i = 0; i < 32; ++i) a += h1[i] * w2[i * 16 + t];
    h2[t] = a > 0.f ? a : expm1f(a);
  }
  __syncthreads();
  if (t == 0) {
    float a = b3[0];
    for (int i = 0; i < 16; ++i) a += h2[i] * w3[i];
    out[g] = a;
  }
}

extern "C" void kernel_launch(void* const* d_in, const int* in_sizes, int n_in,
                              void* d_out, int out_size, void* d_ws, size_t ws_size,
                              hipStream_t stream) {
  (void)in_sizes; (void)n_in; (void)out_size; (void)ws_size;
  const float* x0 = (const float*)d_in[0];
  const int* ei = (const int*)d_in[1];
  const float* ea = (const float*)d_in[2];
  const int* n2s = (const int*)d_in[3];
  const int* s2g = (const int*)d_in[4];
  const float* W1_[3] = {(const float*)d_in[5], (const float*)d_in[11], (const float*)d_in[17]};
  const float* b1_[3] = {(const float*)d_in[6], (const float*)d_in[12], (const float*)d_in[18]};
  const float* W2_[3] = {(const float*)d_in[7], (const float*)d_in[13], (const float*)d_in[19]};
  const float* b2_[3] = {(const float*)d_in[8], (const float*)d_in[14], (const float*)d_in[20]};
  const float* rt_[3] = {(const float*)d_in[9], (const float*)d_in[15], (const float*)d_in[21]};
  const float* bs_[3] = {(const float*)d_in[10], (const float*)d_in[16], (const float*)d_in[22]};
  const float* fc1w = (const float*)d_in[23]; const float* fc1b = (const float*)d_in[24];
  const float* fc2w = (const float*)d_in[25]; const float* fc2b = (const float*)d_in[26];
  const float* fc3w = (const float*)d_in[27]; const float* fc3b = (const float*)d_in[28];
  float* out = (float*)d_out;

  const int* srcp = ei;
  const int* dstp = ei + E_EDGES;

  char* wsb = (char*)d_ws;
  size_t off = 0;
  auto alloc = [&](size_t bytes) {
    void* p = wsb + off;
    off += (bytes + 255) & ~(size_t)255;
    return p;
  };
  // Kpad: L0(CI=16): 2176, L1(CI=32): 4224, L2(CI=64): 8320
  _Float16* Bsw0 = (_Float16*)alloc((size_t)2176 * 32 * 2);
  _Float16* Bsw1 = (_Float16*)alloc((size_t)4224 * 64 * 2);
  _Float16* Bsw2 = (_Float16*)alloc((size_t)8320 * 64 * 2);
  float* msgbuf = (float*)alloc((size_t)KS * E_EDGES * 64 * 4);
  float* x1 = (float*)alloc((size_t)NN * 32 * 4);
  float* x2 = (float*)alloc((size_t)NN * 64 * 4);
  int* hist = (int*)alloc((size_t)NN * 4);
  int* roff = (int*)alloc((size_t)(NN + 1) * 4);
  int* cursor = (int*)alloc((size_t)NN * 4);
  int* eidx = (int*)alloc((size_t)E_EDGES * 4);
  const int npool = 512 * 64 + 512;
  float* pools = (float*)alloc((size_t)npool * 4);
  float* ssum = pools;
  float* scnt = pools + 512 * 64;

  // fused prep+zero: 109056 h8 threads + 2048 hist-int4 + 8320 pool-float4
  const int nprep = 109056 + 2048 + 8320;
  prep_zero_k<<<(nprep + 255) / 256, 256, 0, stream>>>(
      W2_[0], b2_[0], Bsw0, W2_[1], b2_[1], Bsw1, W2_[2], b2_[2], Bsw2,
      (int4*)hist, (float4*)pools);
  hist_k<<<E_EDGES / 256, 256, 0, stream>>>(dstp, hist);
  scan_k<<<1, 1024, 0, stream>>>(hist, roff, cursor);
  scatter_k<<<E_EDGES / 256, 256, 0, stream>>>(dstp, cursor, eidx);

  dim3 mg(E_EDGES / 256, KS);
  msg_mfma_k<16, 32><<<mg, 256, 0, stream>>>(x0, srcp, eidx, ea, W1_[0], b1_[0], Bsw0, msgbuf);
  gather_elu_k<16, 32, false><<<NN / 32, 256, 0, stream>>>(x0, rt_[0], bs_[0], msgbuf, roff, x1, nullptr, nullptr, nullptr);
  msg_mfma_k<32, 64><<<mg, 256, 0, stream>>>(x1, srcp, eidx, ea, W1_[1], b1_[1], Bsw1, msgbuf);
  gather_elu_k<32, 64, false><<<NN / 16, 256, 0, stream>>>(x1, rt_[1], bs_[1], msgbuf, roff, x2, nullptr, nullptr, nullptr);
  msg_mfma_k<64, 64><<<mg, 256, 0, stream>>>(x2, srcp, eidx, ea, W1_[2], b1_[2], Bsw2, msgbuf);
  gather_elu_k<64, 64, true><<<NN / 16, 256, 0, stream>>>(x2, rt_[2], bs_[2], msgbuf, roff, nullptr, n2s, ssum, scnt);

  pg_head_k<<<32, 64, 0, stream>>>(ssum, scnt, s2g, fc1w, fc1b, fc2w, fc2b, fc3w, fc3b, out);
}